// Round 1
// baseline (2813.608 us; speedup 1.0000x reference)
//
#include <hip/hip_runtime.h>
#include <cfloat>
#include <cstdint>

// Problem constants
#define NTOK   131072      // B*H*W = 32*64*64
#define DIM    256
#define NCODE  1024
#define HW     4096        // H*W
#define PLANE  1048576     // DIM*HW (one image's floats)
#define DECAYF 0.9f
#define EPSF   1e-5f

// d_out float offsets (outputs concatenated flat in return order)
#define O_OUT     0
#define O_LOSS    33554432
#define O_IDX     33554433
#define O_NEWEMB  33685505
#define O_NCS     33947649
#define O_NEE     33948673

// d_ws float offsets
#define WS_ENORM  0          // [1024]
#define WS_DW     1024       // [262144]
#define WS_CNT    263168     // [1024]
#define WS_LOSS   264192     // [1]
#define WS_RC     264193     // [1] int
#define WS_LIST   264194     // [16384] int
#define WS_SMOOTH 280578     // [1024]

#define REF_CAP 16384
#define DELTA   0.05f

// ---------------------------------------------------------------- K1: ||e_k||^2
__global__ void k_enorm(const float* __restrict__ embed, float* __restrict__ enorm) {
    int k = blockIdx.x * 256 + threadIdx.x;   // grid 4 x 256
    double s = 0.0;
    for (int d = 0; d < DIM; ++d) {
        float e = embed[(size_t)d * NCODE + k];
        s += (double)e * (double)e;
    }
    enorm[k] = (float)s;
}

// ------------------------------------------------- K2: fp32 distances + top-2 argmin
// Block: 256 threads, tile = 128 tokens x 1024 codes (8 passes of 128 codes).
// Micro-tile 8x8 per thread (16x16 thread grid), DK=32 LDS chunks.
__global__ __launch_bounds__(256, 2) void k_dist(
    const float* __restrict__ x, const float* __restrict__ embed,
    const float* __restrict__ enorm, float* __restrict__ out_idx,
    int* __restrict__ refcnt, int* __restrict__ reflist)
{
    __shared__ __align__(16) float smem[8192];   // Xs[32][128] | Es[32][128]; reused for reduction
    const int tid = threadIdx.x;
    const int tx = tid & 15, ty = tid >> 4;
    const int n0 = blockIdx.x * 128;
    const int b = n0 >> 12, hw0 = n0 & 4095;
    const float* xbase = x + (size_t)b * PLANE + hw0;

    float v1[8], v2[8]; int k1[8];
#pragma unroll
    for (int i = 0; i < 8; ++i) { v1[i] = FLT_MAX; v2[i] = FLT_MAX; k1[i] = 0; }

    const int srow = tid >> 5;         // 0..7
    const int scol = (tid & 31) * 4;   // 0..124

    for (int pass = 0; pass < 8; ++pass) {
        const int kk0 = pass * 128;
        float acc[8][8];
#pragma unroll
        for (int i = 0; i < 8; ++i)
#pragma unroll
            for (int j = 0; j < 8; ++j) acc[i][j] = 0.f;

        for (int dc = 0; dc < 8; ++dc) {
            const int d0 = dc * 32;
            __syncthreads();   // protect previous chunk's readers before overwrite
#pragma unroll
            for (int l = 0; l < 4; ++l) {
                const int r = srow + l * 8;
                *(float4*)&smem[r * 128 + scol] =
                    *(const float4*)&xbase[(size_t)(d0 + r) * HW + scol];
                *(float4*)&smem[4096 + r * 128 + scol] =
                    *(const float4*)&embed[(size_t)(d0 + r) * NCODE + kk0 + scol];
            }
            __syncthreads();
#pragma unroll 8
            for (int d = 0; d < 32; ++d) {
                float4 a0 = *(const float4*)&smem[d * 128 + 4 * tx];
                float4 a1 = *(const float4*)&smem[d * 128 + 64 + 4 * tx];
                float4 b0 = *(const float4*)&smem[4096 + d * 128 + 4 * ty];
                float4 b1 = *(const float4*)&smem[4096 + d * 128 + 64 + 4 * ty];
                float av[8] = {a0.x, a0.y, a0.z, a0.w, a1.x, a1.y, a1.z, a1.w};
                float bv[8] = {b0.x, b0.y, b0.z, b0.w, b1.x, b1.y, b1.z, b1.w};
#pragma unroll
                for (int i = 0; i < 8; ++i)
#pragma unroll
                    for (int j = 0; j < 8; ++j)
                        acc[i][j] = fmaf(av[i], bv[j], acc[i][j]);
            }
        }
        // epilogue: dist = ||e||^2 - 2*dot (||x||^2 constant per token, irrelevant for argmin)
        float en[8]; int kb[8];
#pragma unroll
        for (int jj = 0; jj < 4; ++jj) {
            kb[jj]     = kk0 + 4 * ty + jj;
            kb[4 + jj] = kk0 + 64 + 4 * ty + jj;
            en[jj]     = enorm[kb[jj]];
            en[4 + jj] = enorm[kb[4 + jj]];
        }
#pragma unroll
        for (int i = 0; i < 8; ++i)
#pragma unroll
            for (int j = 0; j < 8; ++j) {   // ascending k within thread -> first-index wins on tie
                float dist = fmaf(-2.f, acc[i][j], en[j]);
                bool lt1 = dist < v1[i];
                bool lt2 = dist < v2[i];
                v2[i] = lt1 ? v1[i] : (lt2 ? dist : v2[i]);
                k1[i] = lt1 ? kb[j] : k1[i];
                v1[i] = lt1 ? dist : v1[i];
            }
    }
    __syncthreads();
    // dump per-thread (v1, v2, k1) to LDS: [ty 0..15][token 0..127][3]
#pragma unroll
    for (int i = 0; i < 8; ++i) {
        int t = (i < 4) ? (4 * tx + i) : (60 + 4 * tx + i);
        float* p = &smem[(ty * 128 + t) * 3];
        p[0] = v1[i]; p[1] = v2[i]; p[2] = __int_as_float(k1[i]);
    }
    __syncthreads();
    if (tid < 128) {
        const int t = tid;
        float bv1 = FLT_MAX, bv2 = FLT_MAX; int bk1 = 0;
        for (int g = 0; g < 16; ++g) {
            const float* p = &smem[(g * 128 + t) * 3];
            float av1 = p[0], av2 = p[1]; int ak1 = __float_as_int(p[2]);
            if (av1 < bv1)       { bv2 = fminf(bv1, av2); bv1 = av1; bk1 = ak1; }
            else if (av1 == bv1) { bk1 = min(bk1, ak1); bv2 = bv1; }   // exact tie -> flag for refine
            else                 { bv2 = fminf(bv2, av1); }
        }
        out_idx[n0 + t] = (float)bk1;
        if (bv2 - bv1 < DELTA) {
            int pos = atomicAdd(refcnt, 1);
            if (pos < REF_CAP) reflist[pos] = n0 + t;
        }
    }
}

// ---------------------------------------- K_refine: exact fp64 argmin for near-ties
__global__ void k_refine(const float* __restrict__ x, const float* __restrict__ embed,
                         float* __restrict__ out_idx, const int* __restrict__ refcnt,
                         const int* __restrict__ reflist)
{
    __shared__ float xs[DIM];
    __shared__ double bestv[256];
    __shared__ int bestk[256];
    const int tid = threadIdx.x;
    const int cnt = min(*refcnt, REF_CAP);
    for (int it = blockIdx.x; it < cnt; it += gridDim.x) {
        const int n = reflist[it];
        const int b = n >> 12, hw = n & 4095;
        xs[tid] = x[(size_t)b * PLANE + (size_t)tid * HW + hw];
        __syncthreads();
        double bv = 1e300; int bk = 0;
        for (int c = 0; c < 4; ++c) {
            const int k = c * 256 + tid;
            double acc = 0.0;
            for (int d = 0; d < DIM; ++d) {
                double df = (double)xs[d] - (double)embed[(size_t)d * NCODE + k];
                acc += df * df;
            }
            if (acc < bv || (acc == bv && k < bk)) { bv = acc; bk = k; }
        }
        bestv[tid] = bv; bestk[tid] = bk;
        __syncthreads();
        for (int s = 128; s > 0; s >>= 1) {
            if (tid < s) {
                double ov = bestv[tid + s]; int ok = bestk[tid + s];
                if (ov < bestv[tid] || (ov == bestv[tid] && ok < bestk[tid])) {
                    bestv[tid] = ov; bestk[tid] = ok;
                }
            }
            __syncthreads();
        }
        if (tid == 0) out_idx[n] = (float)bestk[0];
        __syncthreads();   // before xs reuse next iteration
    }
}

// ------------------- K3: gather quantize -> out, loss partial, dw & count scatter
__global__ __launch_bounds__(256) void k_gather(
    const float* __restrict__ x, const float* __restrict__ embed,
    const float* __restrict__ out_idx, float* __restrict__ out_q,
    float* __restrict__ dw, float* __restrict__ cnt, float* __restrict__ loss_acc)
{
    const int tid = threadIdx.x;
    const int n = blockIdx.x * 256 + tid;      // 512 blocks; 256 consecutive tokens (same b)
    const int b = n >> 12, hw = n & 4095;
    const int idx = (int)out_idx[n];
    const size_t base = (size_t)b * PLANE + hw;
    float lsum = 0.f;
    for (int d = 0; d < DIM; ++d) {
        float e  = embed[(size_t)d * NCODE + idx];
        float xv = x[base + (size_t)d * HW];
        out_q[base + (size_t)d * HW] = e;       // straight-through == quantize values
        float df = xv - e;
        lsum = fmaf(df, df, lsum);
        atomicAdd(&dw[(size_t)d * NCODE + idx], xv);
    }
    atomicAdd(&cnt[idx], 1.0f);
    __shared__ float red[256];
    red[tid] = lsum; __syncthreads();
    for (int s = 128; s > 0; s >>= 1) {
        if (tid < s) red[tid] += red[tid + s];
        __syncthreads();
    }
    if (tid == 0) atomicAdd(loss_acc, red[0]);
}

// ------------------------- K4a: new_cluster_size, smoothing, loss finalize
__global__ __launch_bounds__(1024) void k_fin_cs(
    const float* __restrict__ cs_in, const float* __restrict__ cnt,
    float* __restrict__ out_ncs, float* __restrict__ smooth,
    const float* __restrict__ loss_acc, float* __restrict__ out_loss)
{
    const int k = threadIdx.x;   // 1 block x 1024
    float ncs = cs_in[k] * DECAYF + (1.f - DECAYF) * cnt[k];
    out_ncs[k] = ncs;
    __shared__ float red[1024];
    red[k] = ncs; __syncthreads();
    for (int s = 512; s > 0; s >>= 1) {
        if (k < s) red[k] += red[k + s];
        __syncthreads();
    }
    float n = red[0];
    smooth[k] = n * ((ncs + EPSF) / (n + ncs * EPSF));
    if (k == 0) out_loss[0] = 0.25f * loss_acc[0] / 33554432.f;
}

// ------------------------- K4b: new_ema_embed, new_embed
__global__ __launch_bounds__(256) void k_fin_emb(
    const float* __restrict__ ema, const float* __restrict__ dw,
    const float* __restrict__ smooth, float* __restrict__ out_ne,
    float* __restrict__ out_nee)
{
    const int i = blockIdx.x * 256 + threadIdx.x;   // 1024 blocks -> 262144
    const int k = i & (NCODE - 1);
    float nee = ema[i] * DECAYF + (1.f - DECAYF) * dw[i];
    out_nee[i] = nee;
    out_ne[i] = nee / smooth[k];
}

extern "C" void kernel_launch(void* const* d_in, const int* in_sizes, int n_in,
                              void* d_out, int out_size, void* d_ws, size_t ws_size,
                              hipStream_t stream) {
    const float* x     = (const float*)d_in[0];   // [32, 256, 64, 64]
    const float* embed = (const float*)d_in[1];   // [256, 1024]
    const float* csz   = (const float*)d_in[2];   // [1024]
    const float* ema   = (const float*)d_in[3];   // [256, 1024]
    float* out = (float*)d_out;
    float* ws  = (float*)d_ws;

    // zero dw, count, loss, refine-count (list itself needs no init)
    hipMemsetAsync(ws + WS_DW, 0, (size_t)(WS_RC + 1 - WS_DW) * sizeof(float), stream);

    k_enorm<<<4, 256, 0, stream>>>(embed, ws + WS_ENORM);
    k_dist<<<NTOK / 128, 256, 0, stream>>>(x, embed, ws + WS_ENORM, out + O_IDX,
                                           (int*)(ws + WS_RC), (int*)(ws + WS_LIST));
    k_refine<<<256, 256, 0, stream>>>(x, embed, out + O_IDX,
                                      (const int*)(ws + WS_RC), (const int*)(ws + WS_LIST));
    k_gather<<<NTOK / 256, 256, 0, stream>>>(x, embed, out + O_IDX, out + O_OUT,
                                             ws + WS_DW, ws + WS_CNT, ws + WS_LOSS);
    k_fin_cs<<<1, 1024, 0, stream>>>(csz, ws + WS_CNT, out + O_NCS, ws + WS_SMOOTH,
                                     ws + WS_LOSS, out + O_LOSS);
    k_fin_emb<<<1024, 256, 0, stream>>>(ema, ws + WS_DW, ws + WS_SMOOTH,
                                        out + O_NEWEMB, out + O_NEE);
}

// Round 2
// 1590.592 us; speedup vs baseline: 1.7689x; 1.7689x over previous
//
#include <hip/hip_runtime.h>
#include <cfloat>
#include <cstdint>

// Problem constants
#define NTOK   131072      // B*H*W = 32*64*64
#define DIM    256
#define NCODE  1024
#define HW     4096        // H*W
#define PLANE  1048576     // DIM*HW (one image's floats)
#define DECAYF 0.9f
#define EPSF   1e-5f

// d_out float offsets (outputs concatenated flat in return order)
#define O_OUT     0
#define O_LOSS    33554432
#define O_IDX     33554433
#define O_NEWEMB  33685505
#define O_NCS     33947649
#define O_NEE     33948673

// d_ws float offsets
#define WS_ENORM  0          // [1024]
#define WS_CNT    1024       // [1024]
#define WS_LOSS   2048       // [1]
#define WS_RC     2049       // [1] int
#define WS_LIST   2050       // [16384] int
#define WS_SMOOTH 18434      // [1024]
#define WS_PART   19458      // [nc * 262144] dw partials, layout [chunk][d][k]

#define REF_CAP 16384
#define DELTA   0.05f

// ---------------------------------------------------------------- K1: ||e_k||^2
__global__ void k_enorm(const float* __restrict__ embed, float* __restrict__ enorm) {
    int k = blockIdx.x * 256 + threadIdx.x;   // grid 4 x 256
    double s = 0.0;
    for (int d = 0; d < DIM; ++d) {
        float e = embed[(size_t)d * NCODE + k];
        s += (double)e * (double)e;
    }
    enorm[k] = (float)s;
}

// ------------------------------------------------- K2: fp32 distances + top-2 argmin
// Block: 256 threads, tile = 128 tokens x 1024 codes (8 passes of 128 codes).
// Micro-tile 8x8 per thread (16x16 thread grid), DK=32 LDS chunks.
__global__ __launch_bounds__(256, 2) void k_dist(
    const float* __restrict__ x, const float* __restrict__ embed,
    const float* __restrict__ enorm, float* __restrict__ out_idx,
    int* __restrict__ refcnt, int* __restrict__ reflist)
{
    __shared__ __align__(16) float smem[8192];   // Xs[32][128] | Es[32][128]; reused for reduction
    const int tid = threadIdx.x;
    const int tx = tid & 15, ty = tid >> 4;
    const int n0 = blockIdx.x * 128;
    const int b = n0 >> 12, hw0 = n0 & 4095;
    const float* xbase = x + (size_t)b * PLANE + hw0;

    float v1[8], v2[8]; int k1[8];
#pragma unroll
    for (int i = 0; i < 8; ++i) { v1[i] = FLT_MAX; v2[i] = FLT_MAX; k1[i] = 0; }

    const int srow = tid >> 5;         // 0..7
    const int scol = (tid & 31) * 4;   // 0..124

    for (int pass = 0; pass < 8; ++pass) {
        const int kk0 = pass * 128;
        float acc[8][8];
#pragma unroll
        for (int i = 0; i < 8; ++i)
#pragma unroll
            for (int j = 0; j < 8; ++j) acc[i][j] = 0.f;

        for (int dc = 0; dc < 8; ++dc) {
            const int d0 = dc * 32;
            __syncthreads();   // protect previous chunk's readers before overwrite
#pragma unroll
            for (int l = 0; l < 4; ++l) {
                const int r = srow + l * 8;
                *(float4*)&smem[r * 128 + scol] =
                    *(const float4*)&xbase[(size_t)(d0 + r) * HW + scol];
                *(float4*)&smem[4096 + r * 128 + scol] =
                    *(const float4*)&embed[(size_t)(d0 + r) * NCODE + kk0 + scol];
            }
            __syncthreads();
#pragma unroll 8
            for (int d = 0; d < 32; ++d) {
                float4 a0 = *(const float4*)&smem[d * 128 + 4 * tx];
                float4 a1 = *(const float4*)&smem[d * 128 + 64 + 4 * tx];
                float4 b0 = *(const float4*)&smem[4096 + d * 128 + 4 * ty];
                float4 b1 = *(const float4*)&smem[4096 + d * 128 + 64 + 4 * ty];
                float av[8] = {a0.x, a0.y, a0.z, a0.w, a1.x, a1.y, a1.z, a1.w};
                float bv[8] = {b0.x, b0.y, b0.z, b0.w, b1.x, b1.y, b1.z, b1.w};
#pragma unroll
                for (int i = 0; i < 8; ++i)
#pragma unroll
                    for (int j = 0; j < 8; ++j)
                        acc[i][j] = fmaf(av[i], bv[j], acc[i][j]);
            }
        }
        // epilogue: dist = ||e||^2 - 2*dot (||x||^2 constant per token, irrelevant for argmin)
        float en[8]; int kb[8];
#pragma unroll
        for (int jj = 0; jj < 4; ++jj) {
            kb[jj]     = kk0 + 4 * ty + jj;
            kb[4 + jj] = kk0 + 64 + 4 * ty + jj;
            en[jj]     = enorm[kb[jj]];
            en[4 + jj] = enorm[kb[4 + jj]];
        }
#pragma unroll
        for (int i = 0; i < 8; ++i)
#pragma unroll
            for (int j = 0; j < 8; ++j) {   // ascending k within thread -> first-index wins on tie
                float dist = fmaf(-2.f, acc[i][j], en[j]);
                bool lt1 = dist < v1[i];
                bool lt2 = dist < v2[i];
                v2[i] = lt1 ? v1[i] : (lt2 ? dist : v2[i]);
                k1[i] = lt1 ? kb[j] : k1[i];
                v1[i] = lt1 ? dist : v1[i];
            }
    }
    __syncthreads();
    // dump per-thread (v1, v2, k1) to LDS: [ty 0..15][token 0..127][3]
#pragma unroll
    for (int i = 0; i < 8; ++i) {
        int t = (i < 4) ? (4 * tx + i) : (60 + 4 * tx + i);
        float* p = &smem[(ty * 128 + t) * 3];
        p[0] = v1[i]; p[1] = v2[i]; p[2] = __int_as_float(k1[i]);
    }
    __syncthreads();
    if (tid < 128) {
        const int t = tid;
        float bv1 = FLT_MAX, bv2 = FLT_MAX; int bk1 = 0;
        for (int g = 0; g < 16; ++g) {
            const float* p = &smem[(g * 128 + t) * 3];
            float av1 = p[0], av2 = p[1]; int ak1 = __float_as_int(p[2]);
            if (av1 < bv1)       { bv2 = fminf(bv1, av2); bv1 = av1; bk1 = ak1; }
            else if (av1 == bv1) { bk1 = min(bk1, ak1); bv2 = bv1; }   // exact tie -> flag for refine
            else                 { bv2 = fminf(bv2, av1); }
        }
        out_idx[n0 + t] = (float)bk1;
        if (bv2 - bv1 < DELTA) {
            int pos = atomicAdd(refcnt, 1);
            if (pos < REF_CAP) reflist[pos] = n0 + t;
        }
    }
}

// ---------------------------------------- K_refine: exact fp64 argmin for near-ties
__global__ void k_refine(const float* __restrict__ x, const float* __restrict__ embed,
                         float* __restrict__ out_idx, const int* __restrict__ refcnt,
                         const int* __restrict__ reflist)
{
    __shared__ float xs[DIM];
    __shared__ double bestv[256];
    __shared__ int bestk[256];
    const int tid = threadIdx.x;
    const int cnt = min(*refcnt, REF_CAP);
    for (int it = blockIdx.x; it < cnt; it += gridDim.x) {
        const int n = reflist[it];
        const int b = n >> 12, hw = n & 4095;
        xs[tid] = x[(size_t)b * PLANE + (size_t)tid * HW + hw];
        __syncthreads();
        double bv = 1e300; int bk = 0;
        for (int c = 0; c < 4; ++c) {
            const int k = c * 256 + tid;
            double acc = 0.0;
            for (int d = 0; d < DIM; ++d) {
                double df = (double)xs[d] - (double)embed[(size_t)d * NCODE + k];
                acc += df * df;
            }
            if (acc < bv || (acc == bv && k < bk)) { bv = acc; bk = k; }
        }
        bestv[tid] = bv; bestk[tid] = bk;
        __syncthreads();
        for (int s = 128; s > 0; s >>= 1) {
            if (tid < s) {
                double ov = bestv[tid + s]; int ok = bestk[tid + s];
                if (ov < bestv[tid] || (ov == bestv[tid] && ok < bestk[tid])) {
                    bestv[tid] = ov; bestk[tid] = ok;
                }
            }
            __syncthreads();
        }
        if (tid == 0) out_idx[n] = (float)bestk[0];
        __syncthreads();   // before xs reuse next iteration
    }
}

// ---------------------------------------- K_dw: dw segment-sum via LDS tiles, NO global atomics
// grid = nc chunks x 32 d-slices (8 dims each). LDS tile [1024][9] (pad -> bank (9k+dl)%32, 9 coprime 32).
__global__ __launch_bounds__(256) void k_dw(
    const float* __restrict__ x, const float* __restrict__ out_idx,
    float* __restrict__ part, int nchunk)
{
    __shared__ float tile[NCODE * 9];   // 36 KB
    const int tid = threadIdx.x;
    const int slice = blockIdx.x & 31;          // 0..31 -> dims slice*8..slice*8+7
    const int chunk = blockIdx.x >> 5;          // 0..nchunk-1
    const int d0 = slice * 8;
    for (int i = tid; i < NCODE * 9; i += 256) tile[i] = 0.f;
    __syncthreads();

    const int tok_per = NTOK / nchunk;
    const int nbeg = chunk * tok_per;
    for (int t = tid; t < tok_per; t += 256) {
        const int n = nbeg + t;
        const int b = n >> 12, hw = n & 4095;
        const int k = (int)out_idx[n];
        const float* xb = x + (size_t)b * PLANE + hw;
        float* tp = tile + k * 9;
#pragma unroll
        for (int dl = 0; dl < 8; ++dl) {
            float xv = xb[(size_t)(d0 + dl) * HW];
            unsafeAtomicAdd(&tp[dl], xv);       // ds_add_f32
        }
    }
    __syncthreads();
    // flush tile -> part[chunk][d0+dl][k], coalesced over k
    for (int i = tid; i < 8 * NCODE; i += 256) {
        const int dl = i >> 10, k = i & (NCODE - 1);
        part[((size_t)chunk * DIM + d0 + dl) * NCODE + k] = tile[k * 9 + dl];
    }
}

// ------------------- K_quant: gather quantize -> out, loss partial, count
__global__ __launch_bounds__(256) void k_quant(
    const float* __restrict__ x, const float* __restrict__ embed,
    const float* __restrict__ out_idx, float* __restrict__ out_q,
    float* __restrict__ cnt, float* __restrict__ loss_acc)
{
    const int tid = threadIdx.x;
    const int n = blockIdx.x * 256 + tid;      // 512 blocks; 256 consecutive tokens (same b)
    const int b = n >> 12, hw = n & 4095;
    const int idx = (int)out_idx[n];
    const size_t base = (size_t)b * PLANE + hw;
    float lsum = 0.f;
    for (int d = 0; d < DIM; ++d) {
        float e  = embed[(size_t)d * NCODE + idx];
        float xv = x[base + (size_t)d * HW];
        out_q[base + (size_t)d * HW] = e;       // straight-through == quantize values
        float df = xv - e;
        lsum = fmaf(df, df, lsum);
    }
    atomicAdd(&cnt[idx], 1.0f);
    __shared__ float red[256];
    red[tid] = lsum; __syncthreads();
    for (int s = 128; s > 0; s >>= 1) {
        if (tid < s) red[tid] += red[tid + s];
        __syncthreads();
    }
    if (tid == 0) atomicAdd(loss_acc, red[0]);
}

// ------------------------- K4a: new_cluster_size, smoothing, loss finalize
__global__ __launch_bounds__(1024) void k_fin_cs(
    const float* __restrict__ cs_in, const float* __restrict__ cnt,
    float* __restrict__ out_ncs, float* __restrict__ smooth,
    const float* __restrict__ loss_acc, float* __restrict__ out_loss)
{
    const int k = threadIdx.x;   // 1 block x 1024
    float ncs = cs_in[k] * DECAYF + (1.f - DECAYF) * cnt[k];
    out_ncs[k] = ncs;
    __shared__ float red[1024];
    red[k] = ncs; __syncthreads();
    for (int s = 512; s > 0; s >>= 1) {
        if (k < s) red[k] += red[k + s];
        __syncthreads();
    }
    float n = red[0];
    smooth[k] = n * ((ncs + EPSF) / (n + ncs * EPSF));
    if (k == 0) out_loss[0] = 0.25f * loss_acc[0] / 33554432.f;
}

// ------------------------- K4b: sum dw partials, new_ema_embed, new_embed
__global__ __launch_bounds__(256) void k_fin_emb(
    const float* __restrict__ ema, const float* __restrict__ part,
    const float* __restrict__ smooth, float* __restrict__ out_ne,
    float* __restrict__ out_nee, int nchunk)
{
    const int i = blockIdx.x * 256 + threadIdx.x;   // 1024 blocks -> 262144
    const int k = i & (NCODE - 1);
    float dw = 0.f;
    for (int c = 0; c < nchunk; ++c) dw += part[(size_t)c * (DIM * NCODE) + i];
    float nee = ema[i] * DECAYF + (1.f - DECAYF) * dw;
    out_nee[i] = nee;
    out_ne[i] = nee / smooth[k];
}

extern "C" void kernel_launch(void* const* d_in, const int* in_sizes, int n_in,
                              void* d_out, int out_size, void* d_ws, size_t ws_size,
                              hipStream_t stream) {
    const float* x     = (const float*)d_in[0];   // [32, 256, 64, 64]
    const float* embed = (const float*)d_in[1];   // [256, 1024]
    const float* csz   = (const float*)d_in[2];   // [1024]
    const float* ema   = (const float*)d_in[3];   // [256, 1024]
    float* out = (float*)d_out;
    float* ws  = (float*)d_ws;

    // pick chunk count for dw partials based on available workspace
    int nc = 8;
    while (nc > 1 && ws_size < ((size_t)WS_PART + (size_t)nc * 262144) * sizeof(float))
        nc >>= 1;

    // zero cnt, loss, refine-count (list & partials need no init: partials fully written)
    hipMemsetAsync(ws + WS_CNT, 0, (size_t)(WS_RC + 1 - WS_CNT) * sizeof(float), stream);

    k_enorm<<<4, 256, 0, stream>>>(embed, ws + WS_ENORM);
    k_dist<<<NTOK / 128, 256, 0, stream>>>(x, embed, ws + WS_ENORM, out + O_IDX,
                                           (int*)(ws + WS_RC), (int*)(ws + WS_LIST));
    k_refine<<<256, 256, 0, stream>>>(x, embed, out + O_IDX,
                                      (const int*)(ws + WS_RC), (const int*)(ws + WS_LIST));
    k_dw<<<32 * nc, 256, 0, stream>>>(x, out + O_IDX, ws + WS_PART, nc);
    k_quant<<<NTOK / 256, 256, 0, stream>>>(x, embed, out + O_IDX, out + O_OUT,
                                            ws + WS_CNT, ws + WS_LOSS);
    k_fin_cs<<<1, 1024, 0, stream>>>(csz, ws + WS_CNT, out + O_NCS, ws + WS_SMOOTH,
                                     ws + WS_LOSS, out + O_LOSS);
    k_fin_emb<<<1024, 256, 0, stream>>>(ema, ws + WS_PART, ws + WS_SMOOTH,
                                        out + O_NEWEMB, out + O_NEE, nc);
}

// Round 3
// 1359.566 us; speedup vs baseline: 2.0695x; 1.1699x over previous
//
#include <hip/hip_runtime.h>
#include <cfloat>
#include <cstdint>

typedef unsigned short u16;

// Problem constants
#define NTOK   131072      // B*H*W
#define DIM    256
#define NCODE  1024
#define HW     4096
#define PLANE  1048576     // DIM*HW
#define DECAYF 0.9f
#define EPSF   1e-5f

// d_out float offsets (outputs concatenated in return order)
#define O_OUT     0
#define O_LOSS    33554432
#define O_IDX     33554433
#define O_NEWEMB  33685505
#define O_NCS     33947649
#define O_NEE     33948673

// scratch regions INSIDE O_OUT (float offsets) — k_quant overwrites O_OUT last
#define P_XS      0          // Xs bf16 [131072][256] = 16.7M floats-equiv
#define P_V1      16777216   // [8][131072]
#define P_V2      17825792
#define P_KK      18874368
#define P_VF      19922944   // [131072] final approx v1
#define P_DW      20054016   // [8][262144] dw partials
#define P_BT      22151168   // Bt_sw swizzled tiles, 1 MB

// ws float offsets (tiny, safe for any ws_size)
#define WS_ENORM  0
#define WS_CNT    1024
#define WS_LOSS   2048
#define WS_RC     2049
#define WS_LIST   2050       // [32768]
#define WS_SMOOTH 34818

#define REF_CAP 32768
#define DELTA   0.25f

typedef __attribute__((ext_vector_type(8))) short bf16x8;
typedef __attribute__((ext_vector_type(4))) float f32x4;

__device__ __forceinline__ u16 bf16_rne(float f) {
    unsigned int u = __float_as_uint(f);
    unsigned int r = u + 0x7FFF + ((u >> 16) & 1);
    return (u16)(r >> 16);
}
__device__ __forceinline__ float bf16_to_f(u16 s) {
    return __uint_as_float(((unsigned int)s) << 16);
}
__device__ __forceinline__ void gload_lds16(const void* g, void* l) {
    __builtin_amdgcn_global_load_lds(
        (const __attribute__((address_space(1))) unsigned int*)g,
        (__attribute__((address_space(3))) unsigned int*)l, 16, 0, 0);
}

// ---------------------------------------------------------------- ||e_k||^2
__global__ void k_enorm(const float* __restrict__ embed, float* __restrict__ enorm) {
    int k = blockIdx.x * 256 + threadIdx.x;
    double s = 0.0;
    for (int d = 0; d < DIM; ++d) {
        float e = embed[(size_t)d * NCODE + k];
        s += (double)e * (double)e;
    }
    enorm[k] = (float)s;
}

// ------------------- k_xs: x [b][d][hw] fp32 -> Xs [n][256] bf16 (transpose) + sum(x^2)
__global__ __launch_bounds__(256) void k_xs(const float* __restrict__ x,
                                            u16* __restrict__ Xs,
                                            float* __restrict__ loss_acc)
{
    __shared__ float tile[64 * 65];
    __shared__ float red[256];
    const int tid = threadIdx.x;
    const int blk = blockIdx.x;          // 8192 = 32 b x 4 dc x 64 hwc
    const int b = blk >> 8;
    const int dc = (blk >> 6) & 3;
    const int hwc = blk & 63;
    const int d0 = dc * 64, hw0 = hwc * 64;
    const int r = tid >> 2, s = tid & 3;
    float sq = 0.f;
#pragma unroll
    for (int j = 0; j < 4; ++j) {
        float4 v = *(const float4*)&x[(size_t)b * PLANE + (size_t)(d0 + r) * HW + hw0 + s * 16 + j * 4];
        int c = s * 16 + j * 4;
        tile[r * 65 + c + 0] = v.x; tile[r * 65 + c + 1] = v.y;
        tile[r * 65 + c + 2] = v.z; tile[r * 65 + c + 3] = v.w;
        sq = fmaf(v.x, v.x, sq); sq = fmaf(v.y, v.y, sq);
        sq = fmaf(v.z, v.z, sq); sq = fmaf(v.w, v.w, sq);
    }
    __syncthreads();
    const int tk = tid >> 2, dq = tid & 3;
    u16 us[16];
#pragma unroll
    for (int j = 0; j < 16; ++j)
        us[j] = bf16_rne(tile[(dq * 16 + j) * 65 + tk]);
    size_t ob = (size_t)(b * 4096 + hw0 + tk) * 256 + d0 + dq * 16;
    *(uint4*)&Xs[ob]     = *(uint4*)&us[0];
    *(uint4*)&Xs[ob + 8] = *(uint4*)&us[8];
    red[tid] = sq; __syncthreads();
    for (int st = 128; st > 0; st >>= 1) {
        if (tid < st) red[tid] += red[tid + st];
        __syncthreads();
    }
    if (tid == 0) atomicAdd(loss_acc, red[0]);
}

// ------------------- k_bt: embed -> swizzled bf16 tiles Bt_sw[cc*16+kc][512 granules]
// kc 0..7 = E_hi rows (d = kc*32..), kc 8..15 = E_lo. Granule g of row n stored at slot (g+n)&3.
__global__ __launch_bounds__(256) void k_bt(const float* __restrict__ embed, u16* __restrict__ Bt)
{
    const int tile = blockIdx.x;          // 128 tiles
    const int cc = tile >> 4, kc = tile & 15;
    const int seg = kc >> 3, dbase = (kc & 7) * 32;
    const int tid = threadIdx.x;
#pragma unroll
    for (int g2 = 0; g2 < 2; ++g2) {
        int p = g2 * 256 + tid;
        int n = p >> 2, s = p & 3, lg = (s - n) & 3;
        int code = cc * 128 + n;
        u16 us[8];
#pragma unroll
        for (int e = 0; e < 8; ++e) {
            int d = dbase + lg * 8 + e;
            float E = embed[(size_t)d * NCODE + code];
            u16 hi = bf16_rne(E);
            us[e] = seg ? bf16_rne(E - bf16_to_f(hi)) : hi;
        }
        *(uint4*)&Bt[(size_t)tile * 4096 + (size_t)p * 8] = *(uint4*)&us[0];
    }
}

// ------------------- k_dist: bf16 MFMA GEMM (K=512) + per-chunk top-2
// grid 8192: cc = bx>>10, stripe = bx&1023. Block 128 tok x 128 codes.
__global__ __launch_bounds__(256) void k_dist(
    const u16* __restrict__ Xs, const u16* __restrict__ Bt,
    const float* __restrict__ enorm,
    float* __restrict__ pv1, float* __restrict__ pv2, float* __restrict__ pkk)
{
    __shared__ __align__(16) u16 lds[12288];   // A 8KB | B0 8KB | B1 8KB
    const int tid = threadIdx.x;
    const int w = tid >> 6, l = tid & 63;
    const int cc = blockIdx.x >> 10;
    const int n0 = (blockIdx.x & 1023) * 128;
    const int mh = w & 1, nh = w >> 1;
    const int lane15 = l & 15, quad = l >> 4;

    // staging descriptors: 6 x 16B per thread per kc8 (A: 2 rounds, B0/B1: 4 rounds)
    const u16* src[6];
    u16* dst[6];
#pragma unroll
    for (int r = 0; r < 6; ++r) {
        int p = r * 256 + w * 64 + l;
        dst[r] = &lds[(size_t)(r * 256 + w * 64) * 8];
        if (p < 512) {
            int m = p >> 2, s = p & 3, lg = (s - m) & 3;
            src[r] = Xs + (size_t)(n0 + m) * 256 + lg * 8;
        } else {
            int q = p - 512;
            int kcb = (q >> 9) * 8;
            int qq = q & 511;
            src[r] = Bt + (size_t)(cc * 16 + kcb) * 4096 + (size_t)qq * 8;
        }
    }

    f32x4 acc[4][4];
#pragma unroll
    for (int i = 0; i < 4; ++i)
#pragma unroll
        for (int j = 0; j < 4; ++j) acc[i][j] = (f32x4)0.f;

    for (int kc8 = 0; kc8 < 8; ++kc8) {
        __syncthreads();
#pragma unroll
        for (int r = 0; r < 6; ++r) {
            const u16* s = src[r] + (r < 2 ? (size_t)kc8 * 32 : (size_t)kc8 * 4096);
            gload_lds16(s, dst[r]);
        }
        __syncthreads();

        bf16x8 af[4];
#pragma unroll
        for (int mt = 0; mt < 4; ++mt) {
            int m = mh * 64 + mt * 16 + lane15;
            int slot = (quad + m) & 3;
            af[mt] = *(const bf16x8*)&lds[(size_t)(m * 4 + slot) * 8];
        }
#pragma unroll
        for (int seg = 0; seg < 2; ++seg) {
#pragma unroll
            for (int nt = 0; nt < 4; ++nt) {
                int n = nh * 64 + nt * 16 + lane15;
                int slot = (quad + n) & 3;
                bf16x8 bfr = *(const bf16x8*)&lds[(size_t)(512 + seg * 512 + n * 4 + slot) * 8];
#pragma unroll
                for (int mt = 0; mt < 4; ++mt)
                    acc[mt][nt] = __builtin_amdgcn_mfma_f32_16x16x32_bf16(af[mt], bfr, acc[mt][nt], 0, 0, 0);
            }
        }
    }

    // epilogue: dist = ||e||^2 - 2 dot ; top-2 per token over this cc's 128 codes
    float ev[4]; int ec[4];
#pragma unroll
    for (int nt = 0; nt < 4; ++nt) {
        ec[nt] = cc * 128 + nh * 64 + nt * 16 + lane15;
        ev[nt] = enorm[ec[nt]];
    }
    float r1[4][4], r2[4][4]; int rk[4][4];
#pragma unroll
    for (int mt = 0; mt < 4; ++mt)
#pragma unroll
        for (int rg = 0; rg < 4; ++rg) {
            float v1 = FLT_MAX, v2 = FLT_MAX; int k1 = 1 << 30;
#pragma unroll
            for (int nt = 0; nt < 4; ++nt) {
                float d = fmaf(-2.f, acc[mt][nt][rg], ev[nt]);
                if (d < v1) { v2 = v1; v1 = d; k1 = ec[nt]; }
                else v2 = fminf(v2, d);
            }
            r1[mt][rg] = v1; r2[mt][rg] = v2; rk[mt][rg] = k1;
        }
#pragma unroll
    for (int mask = 1; mask <= 8; mask <<= 1) {
#pragma unroll
        for (int mt = 0; mt < 4; ++mt)
#pragma unroll
            for (int rg = 0; rg < 4; ++rg) {
                float ov1 = __shfl_xor(r1[mt][rg], mask);
                float ov2 = __shfl_xor(r2[mt][rg], mask);
                int   ok  = __shfl_xor(rk[mt][rg], mask);
                if (ov1 < r1[mt][rg] || (ov1 == r1[mt][rg] && ok < rk[mt][rg])) {
                    r2[mt][rg] = fminf(r1[mt][rg], ov2);
                    r1[mt][rg] = ov1; rk[mt][rg] = ok;
                } else {
                    r2[mt][rg] = fminf(r2[mt][rg], ov1);
                }
            }
    }
    __syncthreads();
    float* epi = (float*)lds;   // [2 n-halves][128 tokens][3]
    if (lane15 == 0) {
#pragma unroll
        for (int mt = 0; mt < 4; ++mt)
#pragma unroll
            for (int rg = 0; rg < 4; ++rg) {
                int t = mh * 64 + mt * 16 + quad * 4 + rg;
                float* p = &epi[(nh * 128 + t) * 3];
                p[0] = r1[mt][rg]; p[1] = r2[mt][rg]; p[2] = __int_as_float(rk[mt][rg]);
            }
    }
    __syncthreads();
    if (tid < 128) {
        const float* p0 = &epi[tid * 3];
        const float* p1 = &epi[(128 + tid) * 3];
        float v1 = p0[0], v2 = p0[1]; int k1 = __float_as_int(p0[2]);
        float a1 = p1[0], a2 = p1[1]; int ak = __float_as_int(p1[2]);
        if (a1 < v1 || (a1 == v1 && ak < k1)) { v2 = fminf(v1, a2); v1 = a1; k1 = ak; }
        else v2 = fminf(v2, a1);
        size_t o = (size_t)cc * NTOK + n0 + tid;
        pv1[o] = v1; pv2[o] = v2; pkk[o] = (float)k1;
    }
}

// ------------------- k_amin: combine 8 chunk partials -> idx, vf, refine flags, sum(v1)
__global__ __launch_bounds__(256) void k_amin(
    const float* __restrict__ pv1, const float* __restrict__ pv2, const float* __restrict__ pkk,
    float* __restrict__ out_idx, float* __restrict__ vf, float* __restrict__ loss_acc,
    int* __restrict__ refcnt, int* __restrict__ reflist)
{
    const int n = blockIdx.x * 256 + threadIdx.x;
    float v1 = FLT_MAX, v2 = FLT_MAX; int k1 = 1 << 30;
    for (int cc = 0; cc < 8; ++cc) {
        float a1 = pv1[(size_t)cc * NTOK + n], a2 = pv2[(size_t)cc * NTOK + n];
        int ak = (int)pkk[(size_t)cc * NTOK + n];
        if (a1 < v1 || (a1 == v1 && ak < k1)) { v2 = fminf(v1, a2); v1 = a1; k1 = ak; }
        else v2 = fminf(v2, a1);
    }
    out_idx[n] = (float)k1;
    vf[n] = v1;
    if (v2 - v1 < DELTA) {
        int pos = atomicAdd(refcnt, 1);
        if (pos < REF_CAP) reflist[pos] = n;
    }
    __shared__ float red[256];
    red[threadIdx.x] = v1; __syncthreads();
    for (int s = 128; s > 0; s >>= 1) {
        if (threadIdx.x < s) red[threadIdx.x] += red[threadIdx.x + s];
        __syncthreads();
    }
    if (threadIdx.x == 0) atomicAdd(loss_acc, red[0]);
}

// ------------------- k_refine: exact fp64 argmin for flagged tokens + loss correction
__global__ void k_refine(const float* __restrict__ x, const float* __restrict__ embed,
                         float* __restrict__ out_idx, const int* __restrict__ refcnt,
                         const int* __restrict__ reflist, const float* __restrict__ vf,
                         float* __restrict__ loss_acc)
{
    __shared__ float xs[DIM];
    __shared__ double bestv[256];
    __shared__ int bestk[256];
    __shared__ double sqs;
    const int tid = threadIdx.x;
    const int cnt = min(*refcnt, REF_CAP);
    for (int it = blockIdx.x; it < cnt; it += gridDim.x) {
        const int n = reflist[it];
        const int b = n >> 12, hw = n & 4095;
        float xv = x[(size_t)b * PLANE + (size_t)tid * HW + hw];
        xs[tid] = xv;
        bestv[tid] = (double)xv * (double)xv;
        __syncthreads();
        for (int s = 128; s > 0; s >>= 1) {
            if (tid < s) bestv[tid] += bestv[tid + s];
            __syncthreads();
        }
        if (tid == 0) sqs = bestv[0];
        __syncthreads();
        double bv = 1e300; int bk = 0;
        for (int c = 0; c < 4; ++c) {
            const int k = c * 256 + tid;
            double a = 0.0;
            for (int d = 0; d < DIM; ++d) {
                double df = (double)xs[d] - (double)embed[(size_t)d * NCODE + k];
                a += df * df;
            }
            if (a < bv || (a == bv && k < bk)) { bv = a; bk = k; }
        }
        bestv[tid] = bv; bestk[tid] = bk;
        __syncthreads();
        for (int s = 128; s > 0; s >>= 1) {
            if (tid < s) {
                double ov = bestv[tid + s]; int ok = bestk[tid + s];
                if (ov < bestv[tid] || (ov == bestv[tid] && ok < bestk[tid])) {
                    bestv[tid] = ov; bestk[tid] = ok;
                }
            }
            __syncthreads();
        }
        if (tid == 0) {
            out_idx[n] = (float)bestk[0];
            atomicAdd(loss_acc, (float)((bestv[0] - sqs) - (double)vf[n]));
        }
        __syncthreads();
    }
}

// ------------------- k_cnt: ref_count (post-refine)
__global__ __launch_bounds__(256) void k_cnt(const float* __restrict__ out_idx, float* __restrict__ cnt) {
    const int n = blockIdx.x * 256 + threadIdx.x;
    atomicAdd(&cnt[(int)out_idx[n]], 1.0f);
}

// ------------------- k_dw: dw segment-sum via LDS tiles (nc=8 fixed)
__global__ __launch_bounds__(256) void k_dw(
    const float* __restrict__ x, const float* __restrict__ out_idx, float* __restrict__ part)
{
    __shared__ float tile[NCODE * 9];
    const int tid = threadIdx.x;
    const int slice = blockIdx.x & 31;
    const int chunk = blockIdx.x >> 5;
    const int d0 = slice * 8;
    for (int i = tid; i < NCODE * 9; i += 256) tile[i] = 0.f;
    __syncthreads();
    const int nbeg = chunk * (NTOK / 8);
    for (int t = tid; t < NTOK / 8; t += 256) {
        const int n = nbeg + t;
        const int b = n >> 12, hw = n & 4095;
        const int k = (int)out_idx[n];
        const float* xb = x + (size_t)b * PLANE + hw;
        float* tp = tile + k * 9;
#pragma unroll
        for (int dl = 0; dl < 8; ++dl)
            unsafeAtomicAdd(&tp[dl], xb[(size_t)(d0 + dl) * HW]);
    }
    __syncthreads();
    for (int i = tid; i < 8 * NCODE; i += 256) {
        const int dl = i >> 10, k = i & (NCODE - 1);
        part[((size_t)chunk * DIM + d0 + dl) * NCODE + k] = tile[k * 9 + dl];
    }
}

// ------------------- k_fin_cs: new_cluster_size + smoothing
__global__ __launch_bounds__(1024) void k_fin_cs(
    const float* __restrict__ cs_in, const float* __restrict__ cnt,
    float* __restrict__ out_ncs, float* __restrict__ smooth)
{
    const int k = threadIdx.x;
    float ncs = cs_in[k] * DECAYF + (1.f - DECAYF) * cnt[k];
    out_ncs[k] = ncs;
    __shared__ float red[1024];
    red[k] = ncs; __syncthreads();
    for (int s = 512; s > 0; s >>= 1) {
        if (k < s) red[k] += red[k + s];
        __syncthreads();
    }
    float n = red[0];
    smooth[k] = n * ((ncs + EPSF) / (n + ncs * EPSF));
}

// ------------------- k_fin_emb: sum dw partials, new_ema_embed, new_embed
__global__ __launch_bounds__(256) void k_fin_emb(
    const float* __restrict__ ema, const float* __restrict__ part,
    const float* __restrict__ smooth, float* __restrict__ out_ne, float* __restrict__ out_nee)
{
    const int i = blockIdx.x * 256 + threadIdx.x;
    const int k = i & (NCODE - 1);
    float dw = 0.f;
    for (int c = 0; c < 8; ++c) dw += part[(size_t)c * (DIM * NCODE) + i];
    float nee = ema[i] * DECAYF + (1.f - DECAYF) * dw;
    out_nee[i] = nee;
    out_ne[i] = nee / smooth[k];
}

// ------------------- k_quant: pure gather write (runs LAST, overwrites scratch)
__global__ __launch_bounds__(256) void k_quant(
    const float* __restrict__ embed, const float* __restrict__ out_idx, float* __restrict__ out_q)
{
    const int n = blockIdx.x * 256 + threadIdx.x;
    const int b = n >> 12, hw = n & 4095;
    const int idx = (int)out_idx[n];
    const size_t base = (size_t)b * PLANE + hw;
    for (int d = 0; d < DIM; ++d)
        out_q[base + (size_t)d * HW] = embed[(size_t)d * NCODE + idx];
}

// ------------------- k_loss: finalize scalar
__global__ void k_loss(const float* __restrict__ loss_acc, float* __restrict__ out_loss) {
    out_loss[0] = 0.25f * loss_acc[0] / 33554432.f;
}

extern "C" void kernel_launch(void* const* d_in, const int* in_sizes, int n_in,
                              void* d_out, int out_size, void* d_ws, size_t ws_size,
                              hipStream_t stream) {
    const float* x     = (const float*)d_in[0];
    const float* embed = (const float*)d_in[1];
    const float* csz   = (const float*)d_in[2];
    const float* ema   = (const float*)d_in[3];
    float* out = (float*)d_out;
    float* ws  = (float*)d_ws;

    u16* Xs = (u16*)(out + P_XS);
    u16* Bt = (u16*)(out + P_BT);

    hipMemsetAsync(ws + WS_CNT, 0, (size_t)(WS_RC + 1 - WS_CNT) * sizeof(float), stream);

    k_enorm<<<4, 256, 0, stream>>>(embed, ws + WS_ENORM);
    k_xs<<<8192, 256, 0, stream>>>(x, Xs, ws + WS_LOSS);
    k_bt<<<128, 256, 0, stream>>>(embed, Bt);
    k_dist<<<8192, 256, 0, stream>>>(Xs, Bt, ws + WS_ENORM,
                                     out + P_V1, out + P_V2, out + P_KK);
    k_amin<<<NTOK / 256, 256, 0, stream>>>(out + P_V1, out + P_V2, out + P_KK,
                                           out + O_IDX, out + P_VF, ws + WS_LOSS,
                                           (int*)(ws + WS_RC), (int*)(ws + WS_LIST));
    k_refine<<<256, 256, 0, stream>>>(x, embed, out + O_IDX,
                                      (const int*)(ws + WS_RC), (const int*)(ws + WS_LIST),
                                      out + P_VF, ws + WS_LOSS);
    k_cnt<<<NTOK / 256, 256, 0, stream>>>(out + O_IDX, ws + WS_CNT);
    k_dw<<<256, 256, 0, stream>>>(x, out + O_IDX, out + P_DW);
    k_fin_cs<<<1, 1024, 0, stream>>>(csz, ws + WS_CNT, out + O_NCS, ws + WS_SMOOTH);
    k_fin_emb<<<1024, 256, 0, stream>>>(ema, out + P_DW, ws + WS_SMOOTH,
                                        out + O_NEWEMB, out + O_NEE);
    k_quant<<<NTOK / 256, 256, 0, stream>>>(embed, out + O_IDX, out + O_OUT);
    k_loss<<<1, 1, 0, stream>>>(ws + WS_LOSS, out + O_LOSS);
}